// Round 8
// baseline (5331.653 us; speedup 1.0000x reference)
//
#include <hip/hip_runtime.h>
#include <stdint.h>

#define DEVI __device__ __forceinline__

typedef __attribute__((ext_vector_type(8))) short bf16x8;   // 8 bf16 (4 VGPRs)
typedef __attribute__((ext_vector_type(4))) float f32x4;    // MFMA C/D

static constexpr int D = 4096;    // d_in == d_out == K == N
static constexpr int M = 16384;   // bs*seq rows

// exact RNE float -> bf16 bits
DEVI unsigned short f2bf(float f) {
  union { float f; unsigned u; } a; a.f = f;
  unsigned r = a.u + 0x7fffu + ((a.u >> 16) & 1u);
  return (unsigned short)(r >> 16);
}

// async global->LDS, 16B per lane; LDS dest is wave-uniform base + lane*16
DEVI void gload_lds16(const void* g, void* l) {
  __builtin_amdgcn_global_load_lds(
      (__attribute__((address_space(1))) void*)(uintptr_t)g,
      (__attribute__((address_space(3))) void*)l,
      16, 0, 0);
}

DEVI f32x4 MFMA(bf16x8 a, bf16x8 b, f32x4 c) {
  return __builtin_amdgcn_mfma_f32_16x16x32_bf16(a, b, c, 0, 0, 0);
}

#define ASM_BAR()    asm volatile("s_barrier" ::: "memory")
#define WAIT_VM(N)   asm volatile("s_waitcnt vmcnt(" #N ")" ::: "memory")

// ---------------- Kernel A: w_norm (double) + W -> bf16 ----------------
__global__ __launch_bounds__(256) void k_wnorm(const float* __restrict__ w,
                                               double* __restrict__ wn_d,
                                               unsigned short* __restrict__ wbf) {
  const int col = blockIdx.x * 256 + threadIdx.x;
  const int r0 = blockIdx.y * 256;
  double s = 0.0;
  for (int r = r0; r < r0 + 256; ++r) {
    float v = w[(size_t)r * D + col];
    wbf[(size_t)r * D + col] = f2bf(v);
    s += (double)v * (double)v;
  }
  atomicAdd(&wn_d[col], s);
}

__global__ void k_wnf(const double* __restrict__ wn_d, float* __restrict__ wn_f) {
  int i = blockIdx.x * blockDim.x + threadIdx.x;
  if (i < D) wn_f[i] = (float)wn_d[i];
}

// ---------------- Kernel B: 2:4 prune + variance-correct, -> bf16 -------
__global__ __launch_bounds__(256) void k_prune(const float* __restrict__ x,
                                               const float* __restrict__ wn_f,
                                               unsigned short* __restrict__ xs) {
  const int row = blockIdx.x;
  const float* xr = x + (size_t)row * D;
  unsigned short* xo = xs + (size_t)row * D;
  const int t = threadIdx.x;

  float kept[4][4];
  float sx = 0.f, sxx = 0.f, ss = 0.f, sss = 0.f;

#pragma unroll
  for (int i = 0; i < 4; ++i) {
    const int g = t + i * 256;
    const float4 v  = *(const float4*)(xr + 4 * (size_t)g);
    const float4 wv = *(const float4*)(wn_f + 4 * (size_t)g);
    float xv[4] = {v.x, v.y, v.z, v.w};
    float m[4]  = {fabsf(v.x) * wv.x, fabsf(v.y) * wv.y,
                   fabsf(v.z) * wv.z, fabsf(v.w) * wv.w};
    int i1 = 0;
#pragma unroll
    for (int j = 1; j < 4; ++j) if (m[j] > m[i1]) i1 = j;
    int i2 = (i1 == 0) ? 1 : 0;
#pragma unroll
    for (int j = 0; j < 4; ++j) if (j != i1 && j != i2 && m[j] > m[i2]) i2 = j;
#pragma unroll
    for (int j = 0; j < 4; ++j) {
      bool keep = (j == i1) || (j == i2);
      float kv = keep ? xv[j] : 0.f;
      kept[i][j] = kv;
      sx += xv[j]; sxx += xv[j] * xv[j]; ss += kv; sss += kv * kv;
    }
  }

#pragma unroll
  for (int o = 32; o > 0; o >>= 1) {
    sx  += __shfl_down(sx, o);
    sxx += __shfl_down(sxx, o);
    ss  += __shfl_down(ss, o);
    sss += __shfl_down(sss, o);
  }
  __shared__ float wp[4][4];
  __shared__ float s_scale;
  const int wid = t >> 6, lane = t & 63;
  if (lane == 0) { wp[wid][0] = sx; wp[wid][1] = sxx; wp[wid][2] = ss; wp[wid][3] = sss; }
  __syncthreads();
  if (t == 0) {
    float SX = 0, SXX = 0, SS = 0, SSS = 0;
    for (int u = 0; u < 4; ++u) { SX += wp[u][0]; SXX += wp[u][1]; SS += wp[u][2]; SSS += wp[u][3]; }
    float vx = SXX - SX * SX * (1.f / 4096.f);
    float vs = SSS - SS * SS * (1.f / 4096.f);
    s_scale = sqrtf(vx / vs);
  }
  __syncthreads();
  const float sc = s_scale;

#pragma unroll
  for (int i = 0; i < 4; ++i) {
    const int g = t + i * 256;
    ushort4 o;
    o.x = f2bf(kept[i][0] * sc);
    o.y = f2bf(kept[i][1] * sc);
    o.z = f2bf(kept[i][2] * sc);
    o.w = f2bf(kept[i][3] * sc);
    *(ushort4*)(xo + 4 * (size_t)g) = o;
  }
}

// ---------------- Kernel C: bf16 GEMM, 256x256 tile, anti-phase waves ----
// C[m][n] = sum_k A[m][k]*B[n][k].  BK=32; 3-deep circular LDS regions
// (256x32 bf16 = 16KB): A at 0, B at 49152. 8 waves 2x4, 128x64/wave.
// ANTI-PHASE: waves 0-3 do {READ12 -> MFMA32}, waves 4-7 do {MFMA32 ->
// READ12} per substep, so the two waves sharing each SIMD are in opposite
// roles (one feeds the DS pipe while the other feeds the MFMA pipe).
// setprio(1) around MFMA arbitrates in favor of the MFMA-phase wave (T5's
// required role-split now exists). vmcnt(4)+barrier publish regions exactly
// as in the validated round-5/7 chassis.
__global__ __launch_bounds__(512, 2) void k_gemm(const unsigned short* __restrict__ A,  // [M,K]
                                                 const unsigned short* __restrict__ B,  // [N,K]
                                                 float* __restrict__ C) {               // [M,N]
  extern __shared__ char smem[];   // 98304 bytes

  const int tid  = threadIdx.x;
  const int lane = tid & 63;
  const int wid  = tid >> 6;
  const int wr   = wid >> 2;   // 0..1  (row half)
  const int wc   = wid & 3;    // 0..3  (col quarter)
  const int mfmaFirst = (wid & 4);   // waves 4-7: SIMD-mates of 0-3

  // T1: XCD swizzle (1024 blocks, divisible by 8)
  const int bid = blockIdx.x;
  const int swz = (bid & 7) * 128 + (bid >> 3);
  const int m0 = (swz >> 4) * 256;   // 64 row tiles
  const int n0 = (swz & 15) * 256;   // 16 col tiles

  // staging: region 256 rows x 32 k; thread t -> row t>>2, 16B chunk t&3,
  // chunk XOR-swizzled via pre-swizzled GLOBAL source (LDS dest linear).
  const int rs = tid >> 2;                                  // 0..127
  const int ks = ((tid & 3) ^ ((tid >> 3) & 3)) * 8;        // swizzled k-elem off
  const unsigned short* Ar0 = A + (size_t)(m0 + rs) * D + ks;
  const unsigned short* Ar1 = Ar0 + (size_t)128 * D;
  const unsigned short* Br0 = B + (size_t)(n0 + rs) * D + ks;
  const unsigned short* Br1 = Br0 + (size_t)128 * D;
  char* ldst = smem + tid * 16;

  // frag-read byte offsets within a region (row*64B + swizzled 16B chunk)
  const int swz16 = (((lane >> 4) ^ ((lane >> 1) & 3)) << 4);
  const int aRd = (wr * 128 + (lane & 15)) * 64 + swz16;    // + fm*1024 + region
  const int bRd = (wc * 64 + (lane & 15)) * 64 + swz16;     // + fn*1024 + region

#define STAGE(p, kt) do {                                            \
    const int _ab = (p) * 16384;                                     \
    const int _bb = 49152 + (p) * 16384;                             \
    const int _ko = (kt) * 32;                                       \
    gload_lds16(Ar0 + _ko, ldst + _ab);                              \
    gload_lds16(Ar1 + _ko, ldst + _ab + 8192);                       \
    gload_lds16(Br0 + _ko, ldst + _bb);                              \
    gload_lds16(Br1 + _ko, ldst + _bb + 8192);                       \
  } while (0)

#define READ12(xa, xb, rbase) do {                                   \
    _Pragma("unroll")                                                \
    for (int fm = 0; fm < 8; ++fm)                                   \
      xa[fm] = *(const bf16x8*)(smem + (rbase) * 16384 + aRd + fm * 1024); \
    _Pragma("unroll")                                                \
    for (int fn = 0; fn < 4; ++fn)                                   \
      xb[fn] = *(const bf16x8*)(smem + 49152 + (rbase) * 16384 + bRd + fn * 1024); \
  } while (0)

#define MFMA32(xa, xb) do {                                          \
    __builtin_amdgcn_s_setprio(1);                                   \
    _Pragma("unroll")                                                \
    for (int fm = 0; fm < 8; ++fm)                                   \
      _Pragma("unroll")                                              \
      for (int fn = 0; fn < 4; ++fn)                                 \
        acc[fm][fn] = MFMA(xa[fm], xb[fn], acc[fm][fn]);             \
    __builtin_amdgcn_s_setprio(0);                                   \
  } while (0)

// one K-step, anti-phase: even wave-group reads next operands THEN does
// MFMA; odd group MFMAs first (its operands were read last substep and
// retire during the even group's MFMA window), then reads. sched_barrier(0)
// pins the intra-arm order so both arms aren't canonicalized to read-first.
#define SUBSTEP(cxa, cxb, nxa, nxb) do {                             \
    WAIT_VM(4);                      /* publish region rp's stage */ \
    ASM_BAR();                                                       \
    if (mfmaFirst) {                                                 \
      MFMA32(cxa, cxb);                                              \
      __builtin_amdgcn_sched_barrier(0);                             \
      READ12(nxa, nxb, rp);                                          \
    } else {                                                         \
      READ12(nxa, nxb, rp);                                          \
      __builtin_amdgcn_sched_barrier(0);                             \
      MFMA32(cxa, cxb);                                              \
    }                                                                \
    STAGE(sp, kst);                                                  \
    rp = (rp == 2) ? 0 : rp + 1;                                     \
    sp = (sp == 2) ? 0 : sp + 1;                                     \
    kst = (kst < 127) ? kst + 1 : 127;                               \
  } while (0)

  f32x4 acc[8][4] = {};
  bf16x8 ca[8], na[8];
  bf16x8 cb[4], nb[4];

  // ---- prologue: stage k0,k1,k2 into regions 0,1,2; read step-0 operands
  STAGE(0, 0);
  STAGE(1, 1);
  STAGE(2, 2);
  WAIT_VM(8);          // region 0 retired
  ASM_BAR();
  READ12(ca, cb, 0);

  int rp = 1, sp = 0, kst = 3;
  for (int d = 0; d < 64; ++d) {
    SUBSTEP(ca, cb, na, nb);
    SUBSTEP(na, nb, ca, cb);
  }
#undef SUBSTEP
#undef MFMA32
#undef READ12
#undef STAGE

  // ---- epilogue: C/D layout col=lane&15, row=(lane>>4)*4+i ----
  const int orow = (lane >> 4) * 4;
  const int ocol = lane & 15;
  float* Cw = C + (size_t)(m0 + wr * 128 + orow) * D + n0 + wc * 64 + ocol;
#pragma unroll
  for (int fm = 0; fm < 8; ++fm)
#pragma unroll
    for (int fn = 0; fn < 4; ++fn)
#pragma unroll
      for (int i = 0; i < 4; ++i)
        Cw[(size_t)(fm * 16 + i) * D + fn * 16] = acc[fm][fn][i];
}

extern "C" void kernel_launch(void* const* d_in, const int* in_sizes, int n_in,
                              void* d_out, int out_size, void* d_ws, size_t ws_size,
                              hipStream_t stream) {
  const float* x = (const float*)d_in[0];   // [4,4096,4096] fp32
  const float* w = (const float*)d_in[1];   // [4096,4096] fp32
  float* out = (float*)d_out;               // [16384,4096] fp32

  char* ws = (char*)d_ws;
  double* wn_d = (double*)ws;                                   // 32 KB
  float* wn_f = (float*)(ws + 32768);                           // 16 KB
  unsigned short* wbf = (unsigned short*)(ws + 49152);          // 33.5 MB
  unsigned short* xsb = (unsigned short*)(ws + 49152 + (size_t)D * D * 2);  // 134 MB

  hipMemsetAsync(wn_d, 0, D * sizeof(double), stream);
  k_wnorm<<<dim3(16, 16), 256, 0, stream>>>(w, wn_d, wbf);
  k_wnf<<<16, 256, 0, stream>>>(wn_d, wn_f);
  k_prune<<<M, 256, 0, stream>>>(x, wn_f, xsb);
  k_gemm<<<dim3((M / 256) * (D / 256)), 512, 98304, stream>>>(xsb, wbf, out);
}

// Round 9
// 629.125 us; speedup vs baseline: 8.4747x; 8.4747x over previous
//
#include <hip/hip_runtime.h>
#include <stdint.h>

#define DEVI __device__ __forceinline__

typedef __attribute__((ext_vector_type(8))) short bf16x8;   // 8 bf16 (4 VGPRs)
typedef __attribute__((ext_vector_type(4))) float f32x4;    // MFMA C/D

static constexpr int D = 4096;    // d_in == d_out == K == N
static constexpr int M = 16384;   // bs*seq rows

// exact RNE float -> bf16 bits
DEVI unsigned short f2bf(float f) {
  union { float f; unsigned u; } a; a.f = f;
  unsigned r = a.u + 0x7fffu + ((a.u >> 16) & 1u);
  return (unsigned short)(r >> 16);
}

// async global->LDS, 16B per lane; LDS dest is wave-uniform base + lane*16
DEVI void gload_lds16(const void* g, void* l) {
  __builtin_amdgcn_global_load_lds(
      (__attribute__((address_space(1))) void*)(uintptr_t)g,
      (__attribute__((address_space(3))) void*)l,
      16, 0, 0);
}

DEVI f32x4 MFMA(bf16x8 a, bf16x8 b, f32x4 c) {
  return __builtin_amdgcn_mfma_f32_16x16x32_bf16(a, b, c, 0, 0, 0);
}

#define ASM_BAR()    asm volatile("s_barrier" ::: "memory")
#define WAIT_VM(N)   asm volatile("s_waitcnt vmcnt(" #N ")" ::: "memory")

// ---------------- Kernel A: w_norm (double) + W -> bf16 ----------------
__global__ __launch_bounds__(256) void k_wnorm(const float* __restrict__ w,
                                               double* __restrict__ wn_d,
                                               unsigned short* __restrict__ wbf) {
  const int col = blockIdx.x * 256 + threadIdx.x;
  const int r0 = blockIdx.y * 256;
  double s = 0.0;
  for (int r = r0; r < r0 + 256; ++r) {
    float v = w[(size_t)r * D + col];
    wbf[(size_t)r * D + col] = f2bf(v);
    s += (double)v * (double)v;
  }
  atomicAdd(&wn_d[col], s);
}

__global__ void k_wnf(const double* __restrict__ wn_d, float* __restrict__ wn_f) {
  int i = blockIdx.x * blockDim.x + threadIdx.x;
  if (i < D) wn_f[i] = (float)wn_d[i];
}

// ---------------- Kernel B: 2:4 prune + variance-correct, -> bf16 -------
__global__ __launch_bounds__(256) void k_prune(const float* __restrict__ x,
                                               const float* __restrict__ wn_f,
                                               unsigned short* __restrict__ xs) {
  const int row = blockIdx.x;
  const float* xr = x + (size_t)row * D;
  unsigned short* xo = xs + (size_t)row * D;
  const int t = threadIdx.x;

  float kept[4][4];
  float sx = 0.f, sxx = 0.f, ss = 0.f, sss = 0.f;

#pragma unroll
  for (int i = 0; i < 4; ++i) {
    const int g = t + i * 256;
    const float4 v  = *(const float4*)(xr + 4 * (size_t)g);
    const float4 wv = *(const float4*)(wn_f + 4 * (size_t)g);
    float xv[4] = {v.x, v.y, v.z, v.w};
    float m[4]  = {fabsf(v.x) * wv.x, fabsf(v.y) * wv.y,
                   fabsf(v.z) * wv.z, fabsf(v.w) * wv.w};
    int i1 = 0;
#pragma unroll
    for (int j = 1; j < 4; ++j) if (m[j] > m[i1]) i1 = j;
    int i2 = (i1 == 0) ? 1 : 0;
#pragma unroll
    for (int j = 0; j < 4; ++j) if (j != i1 && j != i2 && m[j] > m[i2]) i2 = j;
#pragma unroll
    for (int j = 0; j < 4; ++j) {
      bool keep = (j == i1) || (j == i2);
      float kv = keep ? xv[j] : 0.f;
      kept[i][j] = kv;
      sx += xv[j]; sxx += xv[j] * xv[j]; ss += kv; sss += kv * kv;
    }
  }

#pragma unroll
  for (int o = 32; o > 0; o >>= 1) {
    sx  += __shfl_down(sx, o);
    sxx += __shfl_down(sxx, o);
    ss  += __shfl_down(ss, o);
    sss += __shfl_down(sss, o);
  }
  __shared__ float wp[4][4];
  __shared__ float s_scale;
  const int wid = t >> 6, lane = t & 63;
  if (lane == 0) { wp[wid][0] = sx; wp[wid][1] = sxx; wp[wid][2] = ss; wp[wid][3] = sss; }
  __syncthreads();
  if (t == 0) {
    float SX = 0, SXX = 0, SS = 0, SSS = 0;
    for (int u = 0; u < 4; ++u) { SX += wp[u][0]; SXX += wp[u][1]; SS += wp[u][2]; SSS += wp[u][3]; }
    float vx = SXX - SX * SX * (1.f / 4096.f);
    float vs = SSS - SS * SS * (1.f / 4096.f);
    s_scale = sqrtf(vx / vs);
  }
  __syncthreads();
  const float sc = s_scale;

#pragma unroll
  for (int i = 0; i < 4; ++i) {
    const int g = t + i * 256;
    ushort4 o;
    o.x = f2bf(kept[i][0] * sc);
    o.y = f2bf(kept[i][1] * sc);
    o.z = f2bf(kept[i][2] * sc);
    o.w = f2bf(kept[i][3] * sc);
    *(ushort4*)(xo + 4 * (size_t)g) = o;
  }
}

// ---------------- Kernel C: bf16 GEMM, 256x256 tile, 16 waves x 64x64 ----
// C[m][n] = sum_k A[m][k]*B[n][k].  BK=32; 3-deep circular LDS regions
// (256x32 bf16 = 16KB): A at 0, B at 49152. 16 waves (1024 thr) in a 4x4
// grid, 64x64 per wave -> acc is only 64 VGPR/wave, total ~110 regs ->
// 4 waves/SIMD. Single-buffered operand reads (read -> MFMA in-phase);
// with 4 independent wave streams per SIMD, TLP hides each wave's LDS
// wait (the m97/m114 overlap mechanism) instead of intra-wave ILP.
// Per substep t: vmcnt(2) publishes region k(t); barrier; 8 ds_read;
// 16 MFMA (compiler-managed lgkm); STAGE k(t+2) into region((t+2)%3)
// (that region's last reads happened at t-1, barrier separates). Stage
// lead = 2 substeps >> HBM latency; vmcnt never drains to 0.
__global__ __launch_bounds__(1024, 4) void k_gemm(const unsigned short* __restrict__ A,  // [M,K]
                                                  const unsigned short* __restrict__ B,  // [N,K]
                                                  float* __restrict__ C) {               // [M,N]
  extern __shared__ char smem[];   // 98304 bytes

  const int tid  = threadIdx.x;
  const int lane = tid & 63;
  const int wid  = tid >> 6;   // 0..15
  const int qr   = wid >> 2;   // 0..3  (row quarter)
  const int qc   = wid & 3;    // 0..3  (col quarter)

  // T1: XCD swizzle (1024 blocks, divisible by 8)
  const int bid = blockIdx.x;
  const int swz = (bid & 7) * 128 + (bid >> 3);
  const int m0 = (swz >> 4) * 256;   // 64 row tiles
  const int n0 = (swz & 15) * 256;   // 16 col tiles

  // staging: region 256 rows x 32 k; thread t -> row t>>2, 16B chunk t&3,
  // chunk XOR-swizzled via pre-swizzled GLOBAL source (LDS dest linear).
  // 1024 threads x 16B = 16KB = one full region per gload instruction.
  const int rs = tid >> 2;                                  // 0..255
  const int ks = ((tid & 3) ^ ((tid >> 3) & 3)) * 8;        // swizzled k-elem off
  const unsigned short* Ar = A + (size_t)(m0 + rs) * D + ks;
  const unsigned short* Br = B + (size_t)(n0 + rs) * D + ks;
  char* ldst = smem + tid * 16;

  // frag-read byte offsets within a region (row*64B + swizzled 16B chunk)
  const int swz16 = (((lane >> 4) ^ ((lane >> 1) & 3)) << 4);
  const int aRd = (qr * 64 + (lane & 15)) * 64 + swz16;     // + fm*1024 + region
  const int bRd = (qc * 64 + (lane & 15)) * 64 + swz16;     // + fn*1024 + region

#define STAGE(p, kt) do {                                            \
    const int _ko = (kt) * 32;                                       \
    gload_lds16(Ar + _ko, ldst + (p) * 16384);                       \
    gload_lds16(Br + _ko, ldst + 49152 + (p) * 16384);               \
  } while (0)

  f32x4 acc[4][4] = {};

  // ---- prologue: stage k0->r0, k1->r1 (k2 staged inside substep 0) ----
  STAGE(0, 0);
  STAGE(1, 1);

  int rp = 0;          // region holding k(t)
  int sp = 2;          // region to stage k(t+2) into
  int kst = 2;         // next k-index to stage

  for (int t = 0; t < 128; ++t) {
    WAIT_VM(2);        // FIFO: retires stage(t) -> region rp published
    ASM_BAR();

    bf16x8 a0, a1, a2, a3, b0, b1, b2, b3;
    {
      const char* ab = smem + rp * 16384 + aRd;
      const char* bb = smem + 49152 + rp * 16384 + bRd;
      a0 = *(const bf16x8*)(ab);
      a1 = *(const bf16x8*)(ab + 1024);
      a2 = *(const bf16x8*)(ab + 2048);
      a3 = *(const bf16x8*)(ab + 3072);
      b0 = *(const bf16x8*)(bb);
      b1 = *(const bf16x8*)(bb + 1024);
      b2 = *(const bf16x8*)(bb + 2048);
      b3 = *(const bf16x8*)(bb + 3072);
    }
    __builtin_amdgcn_s_setprio(1);
    acc[0][0] = MFMA(a0, b0, acc[0][0]);
    acc[0][1] = MFMA(a0, b1, acc[0][1]);
    acc[0][2] = MFMA(a0, b2, acc[0][2]);
    acc[0][3] = MFMA(a0, b3, acc[0][3]);
    acc[1][0] = MFMA(a1, b0, acc[1][0]);
    acc[1][1] = MFMA(a1, b1, acc[1][1]);
    acc[1][2] = MFMA(a1, b2, acc[1][2]);
    acc[1][3] = MFMA(a1, b3, acc[1][3]);
    acc[2][0] = MFMA(a2, b0, acc[2][0]);
    acc[2][1] = MFMA(a2, b1, acc[2][1]);
    acc[2][2] = MFMA(a2, b2, acc[2][2]);
    acc[2][3] = MFMA(a2, b3, acc[2][3]);
    acc[3][0] = MFMA(a3, b0, acc[3][0]);
    acc[3][1] = MFMA(a3, b1, acc[3][1]);
    acc[3][2] = MFMA(a3, b2, acc[3][2]);
    acc[3][3] = MFMA(a3, b3, acc[3][3]);
    __builtin_amdgcn_s_setprio(0);

    // stage k(t+2) into region((t+2)%3): its last reads were at t-1,
    // separated from this write by the barrier at the top of substep t.
    STAGE(sp, kst);
    kst = (kst < 127) ? kst + 1 : 127;   // clamped tail (dup-stage harmless)
    rp = (rp == 2) ? 0 : rp + 1;
    sp = (sp == 2) ? 0 : sp + 1;
  }
#undef STAGE

  // ---- epilogue: C/D layout col=lane&15, row=(lane>>4)*4+i ----
  const int orow = (lane >> 4) * 4;
  const int ocol = lane & 15;
  float* Cw = C + (size_t)(m0 + qr * 64 + orow) * D + n0 + qc * 64 + ocol;
#pragma unroll
  for (int fm = 0; fm < 4; ++fm)
#pragma unroll
    for (int fn = 0; fn < 4; ++fn)
#pragma unroll
      for (int i = 0; i < 4; ++i)
        Cw[(size_t)(fm * 16 + i) * D + fn * 16] = acc[fm][fn][i];
}

extern "C" void kernel_launch(void* const* d_in, const int* in_sizes, int n_in,
                              void* d_out, int out_size, void* d_ws, size_t ws_size,
                              hipStream_t stream) {
  const float* x = (const float*)d_in[0];   // [4,4096,4096] fp32
  const float* w = (const float*)d_in[1];   // [4096,4096] fp32
  float* out = (float*)d_out;               // [16384,4096] fp32

  char* ws = (char*)d_ws;
  double* wn_d = (double*)ws;                                   // 32 KB
  float* wn_f = (float*)(ws + 32768);                           // 16 KB
  unsigned short* wbf = (unsigned short*)(ws + 49152);          // 33.5 MB
  unsigned short* xsb = (unsigned short*)(ws + 49152 + (size_t)D * D * 2);  // 134 MB

  hipMemsetAsync(wn_d, 0, D * sizeof(double), stream);
  k_wnorm<<<dim3(16, 16), 256, 0, stream>>>(w, wn_d, wbf);
  k_wnf<<<16, 256, 0, stream>>>(wn_d, wn_f);
  k_prune<<<M, 256, 0, stream>>>(x, wn_f, xsb);
  k_gemm<<<dim3((M / 256) * (D / 256)), 1024, 98304, stream>>>(xsb, wbf, out);
}